// Round 12
// baseline (318.188 us; speedup 1.0000x reference)
//
#include <hip/hip_runtime.h>
#include <stdint.h>
#include <stddef.h>

typedef __bf16 bf16_t;
typedef bf16_t bf16x4 __attribute__((ext_vector_type(4)));
typedef bf16_t bf16x8 __attribute__((ext_vector_type(8)));
typedef float f32x4 __attribute__((ext_vector_type(4)));

#define MFMA_BF16(A_, B_, C_) __builtin_amdgcn_mfma_f32_16x16x32_bf16(A_, B_, C_, 0, 0, 0)

static constexpr int Lseq = 2048;
static constexpr int Dmod = 1024;
static constexpr int Hn   = 16;
static constexpr int HDim = 64;
static constexpr size_t M1 = 1u << 20;  // 1M elements

// XOR-swizzled offset (elements) into a [rows][64] bf16 tile, 16B chunks
__device__ __forceinline__ int swz(int row, int chunk) {
  return row * 64 + ((chunk ^ (row & 7)) << 3);
}

// async global->LDS DMA, 16B per lane, wave-uniform LDS base
__device__ __forceinline__ void async_ld16(const bf16_t* g, bf16_t* l) {
  __builtin_amdgcn_global_load_lds(
      (const __attribute__((address_space(1))) void*)g,
      (__attribute__((address_space(3))) void*)l, 16, 0, 0);
}

// ---------------------------------------------------------------------------
// cvt_kernel: fp32 -> bf16, 16B stores. wq additionally pre-scaled by
// 0.125*log2(e) so attention scores arrive ready for exp2 (no per-elem mul).
// ---------------------------------------------------------------------------
__global__ __launch_bounds__(256) void cvt_kernel(
    const float* __restrict__ Q, const float* __restrict__ K,
    const float* __restrict__ V, const float* __restrict__ wq,
    const float* __restrict__ wk, const float* __restrict__ wv,
    const float* __restrict__ wout, bf16_t* __restrict__ wsb)
{
  const int s = blockIdx.z;
  const float* __restrict__ src;
  if      (s < 4)   src = Q    + (size_t)s * M1;
  else if (s < 8)   src = K    + (size_t)(s - 4) * M1;
  else if (s < 12)  src = V    + (size_t)(s - 8) * M1;
  else if (s == 12) src = wq;
  else if (s == 13) src = wk;
  else if (s == 14) src = wv;
  else              src = wout;
  bf16_t* __restrict__ dst = wsb + (size_t)s * M1;
  const float scale = (s == 12) ? 0.18033688f : 1.0f;  // 0.125 * log2(e)

  const int idx = blockIdx.x * 256 + threadIdx.x;  // 0..131071 (1M/8)
  float4 a = ((const float4*)src)[idx * 2];
  float4 b = ((const float4*)src)[idx * 2 + 1];
  bf16x8 o;
  o[0] = (bf16_t)(a.x * scale); o[1] = (bf16_t)(a.y * scale);
  o[2] = (bf16_t)(a.z * scale); o[3] = (bf16_t)(a.w * scale);
  o[4] = (bf16_t)(b.x * scale); o[5] = (bf16_t)(b.y * scale);
  o[6] = (bf16_t)(b.z * scale); o[7] = (bf16_t)(b.w * scale);
  ((bf16x8*)dst)[idx] = o;
}

// ---------------------------------------------------------------------------
// proj_kernel: all-bf16 GEMM P = X @ W^T. 128(M)x64(N) tile, BK=64,
// single-buffered LDS DMA. Grid (x=m, y=n, z): XCD = m%8 locality.
//   z=0 -> q [B,H,L,HD]; z=1 -> k [B,H,L,HD]; z=2 -> v [B,H,HD,L]
// ---------------------------------------------------------------------------
__global__ __launch_bounds__(256) void proj_kernel(
    const bf16_t* __restrict__ Qbf, const bf16_t* __restrict__ Kbf,
    const bf16_t* __restrict__ Vbf, const bf16_t* __restrict__ wqb,
    const bf16_t* __restrict__ wkb, const bf16_t* __restrict__ wvb,
    bf16_t* __restrict__ qo, bf16_t* __restrict__ ko, bf16_t* __restrict__ vo)
{
  const int z = blockIdx.z;
  const bf16_t* __restrict__ A  = (z == 0) ? Qbf : (z == 1) ? Kbf : Vbf;
  const bf16_t* __restrict__ Bw = (z == 0) ? wqb : (z == 1) ? wkb : wvb;
  bf16_t* __restrict__ dst      = (z == 0) ? qo  : (z == 1) ? ko  : vo;

  __shared__ __align__(16) bf16_t As[128 * 64];  // 16 KB
  __shared__ __align__(16) bf16_t Bs[64 * 64];   //  8 KB

  const int tid  = threadIdx.x;
  const int wave = tid >> 6;
  const int lane = tid & 63;
  const int quad = lane >> 4;
  const int l16  = lane & 15;
  const int wm   = (wave & 1) * 64;
  const int wn   = (wave >> 1) * 32;
  const int m0   = blockIdx.x * 128;   // x = m (32): same-A blocks -> same XCD
  const int n0   = blockIdx.y * 64;    // y = n (16)

  const int srow8  = lane >> 3;
  const int schunk = (lane & 7) ^ srow8;

  f32x4 acc[4][2];
#pragma unroll
  for (int i = 0; i < 4; ++i)
#pragma unroll
    for (int j = 0; j < 2; ++j)
#pragma unroll
      for (int e = 0; e < 4; ++e) acc[i][j][e] = 0.0f;

  for (int kt = 0; kt < 16; ++kt) {
    const int k0 = kt * 64;
    __syncthreads();  // LDS reads of previous iter done
#pragma unroll
    for (int i = 0; i < 4; ++i) {
      const int rb = wave * 32 + i * 8;
      async_ld16(&A[(size_t)(m0 + rb + srow8) * Dmod + k0 + schunk * 8], &As[rb * 64]);
    }
#pragma unroll
    for (int i = 0; i < 2; ++i) {
      const int rb = wave * 16 + i * 8;
      async_ld16(&Bw[(size_t)(n0 + rb + srow8) * Dmod + k0 + schunk * 8], &Bs[rb * 64]);
    }
    __syncthreads();  // DMA drained

    bf16x8 af[4][2], bfr[2][2];
#pragma unroll
    for (int mt = 0; mt < 4; ++mt) {
      const int row = wm + mt * 16 + l16;
      af[mt][0] = *(const bf16x8*)&As[swz(row, quad)];
      af[mt][1] = *(const bf16x8*)&As[swz(row, quad + 4)];
    }
#pragma unroll
    for (int nt = 0; nt < 2; ++nt) {
      const int row = wn + nt * 16 + l16;
      bfr[nt][0] = *(const bf16x8*)&Bs[swz(row, quad)];
      bfr[nt][1] = *(const bf16x8*)&Bs[swz(row, quad + 4)];
    }
#pragma unroll
    for (int mt = 0; mt < 4; ++mt)
#pragma unroll
      for (int nt = 0; nt < 2; ++nt) {
        acc[mt][nt] = MFMA_BF16(af[mt][0], bfr[nt][0], acc[mt][nt]);
        acc[mt][nt] = MFMA_BF16(af[mt][1], bfr[nt][1], acc[mt][nt]);
      }
  }

#pragma unroll
  for (int mt = 0; mt < 4; ++mt) {
    const int grb = m0 + wm + mt * 16 + quad * 4;
    const int bb  = grb >> 11;
    const int lb  = grb & 2047;
#pragma unroll
    for (int nt = 0; nt < 2; ++nt) {
      const int gc = n0 + wn + nt * 16 + l16;
      const int h  = gc >> 6;
      const int hd = gc & 63;
      if (z == 2) {
        bf16x4 pk;
#pragma unroll
        for (int r = 0; r < 4; ++r) pk[r] = (bf16_t)acc[mt][nt][r];
        *(bf16x4*)&dst[(((size_t)(bb * Hn + h) * HDim + hd) << 11) + lb] = pk;
      } else {
#pragma unroll
        for (int r = 0; r < 4; ++r)
          dst[(((size_t)(bb * Hn + h) * Lseq + lb + r) << 6) + hd] = (bf16_t)acc[mt][nt][r];
      }
    }
  }
}

// ---------------------------------------------------------------------------
// attn_kernel: causal flash attention, BARRIER-FREE K-loop. R9 shape
// (4 waves x 16 q-rows, 1024 blocks, LPT, XCD=bh%8) but K/V fragments are
// loaded DIRECTLY global->VGPR (both operand layouts are 16B-contiguous in
// the chosen global layouts) — no Ks/Vs LDS, no DMA, no __syncthreads.
// Waves run independently; K/V tiles are L2-resident (~27 TB/s agg < 34.5
// ceiling). LDS holds only the per-wave P round-trip (9.2 KB).
// Scores pre-scaled (wq folded) -> exp2 directly. Rowsum via ones-MFMA.
// ---------------------------------------------------------------------------
__global__ __launch_bounds__(256) void attn_kernel(
    const bf16_t* __restrict__ q, const bf16_t* __restrict__ k,
    const bf16_t* __restrict__ v, bf16_t* __restrict__ ctx)
{
  const int bh = blockIdx.x;            // 0..31  (fast dim -> XCD = bh%8)
  const int qt = 31 - blockIdx.y;       // LPT: longest blocks first
  const int bb = bh >> 4;
  const int h  = bh & 15;
  const int q0 = qt * 64;

  const int tid  = threadIdx.x;
  const int wave = tid >> 6;
  const int lane = tid & 63;
  const int quad = lane >> 4;
  const int l16  = lane & 15;

  __shared__ __align__(16) bf16_t Ps[4][16][72]; // 9 KB (per-wave, no barrier)

  const bf16_t* __restrict__ qb = q + (size_t)bh * (Lseq * HDim);
  const bf16_t* __restrict__ kb = k + (size_t)bh * (Lseq * HDim);
  const bf16_t* __restrict__ vb = v + (size_t)bh * (HDim * Lseq);

  bf16x8 ones;
#pragma unroll
  for (int i = 0; i < 8; ++i) ones[i] = (bf16_t)1.0f;

  const int qrow = q0 + wave * 16 + l16;
  bf16x8 qf0 = *(const bf16x8*)&qb[(size_t)qrow * HDim + quad * 8];
  bf16x8 qf1 = *(const bf16x8*)&qb[(size_t)qrow * HDim + 32 + quad * 8];

  // per-lane K/V row bases (K: row = key, advances by 64 keys per jt;
  // V: row = d, fixed; column j0 advances per jt)
  const bf16_t* __restrict__ krow0 = kb + (size_t)l16 * HDim + quad * 8;
  const bf16_t* __restrict__ vrow0 = vb + (size_t)l16 * Lseq + quad * 8;

  f32x4 o[4];
  f32x4 lacc;
#pragma unroll
  for (int e = 0; e < 4; ++e) lacc[e] = 0.0f;
#pragma unroll
  for (int nt = 0; nt < 4; ++nt)
#pragma unroll
    for (int e = 0; e < 4; ++e) o[nt][e] = 0.0f;

  for (int jt = 0; jt <= qt; ++jt) {
    const int j0 = jt * 64;

    // K fragments direct from global (L2): rows j0+nt*16+l16, 2x16B each
    bf16x8 kf[4][2];
#pragma unroll
    for (int nt = 0; nt < 4; ++nt) {
      const bf16_t* kr = krow0 + (size_t)(j0 + nt * 16) * HDim;
      kf[nt][0] = *(const bf16x8*)kr;
      kf[nt][1] = *(const bf16x8*)(kr + 32);
    }

    // S^T = K Q^T  (m=key, n=query); scores pre-scaled for exp2
    f32x4 s[4];
#pragma unroll
    for (int nt = 0; nt < 4; ++nt) {
#pragma unroll
      for (int e = 0; e < 4; ++e) s[nt][e] = 0.0f;
      s[nt] = MFMA_BF16(kf[nt][0], qf0, s[nt]);
      s[nt] = MFMA_BF16(kf[nt][1], qf1, s[nt]);
    }

    // V fragments direct from global (L2): rows d=nt*16+l16, cols j0+...
    bf16x8 vf[4][2];
#pragma unroll
    for (int nt = 0; nt < 4; ++nt) {
      const bf16_t* vr = vrow0 + (size_t)nt * 16 * Lseq + j0;
      vf[nt][0] = *(const bf16x8*)vr;
      vf[nt][1] = *(const bf16x8*)(vr + 32);
    }

    // exp2 (scale pre-folded into wq), causal mask on diagonal tile only
    const bool diag = (jt == qt);
#pragma unroll
    for (int nt = 0; nt < 4; ++nt) {
      bf16x4 pk;
#pragma unroll
      for (int r = 0; r < 4; ++r) {
        float val = s[nt][r];
        if (diag && (nt * 16 + quad * 4 + r > wave * 16 + l16)) val = -1e30f;
        pk[r] = (bf16_t)__builtin_amdgcn_exp2f(val);
      }
      *(bf16x4*)&Ps[wave][l16][nt * 16 + quad * 4] = pk;
    }

    // P fragments (A-layout) — wave-local LDS round-trip, lgkmcnt only
    bf16x8 pf0 = *(const bf16x8*)&Ps[wave][l16][quad * 8];
    bf16x8 pf1 = *(const bf16x8*)&Ps[wave][l16][32 + quad * 8];

    lacc = MFMA_BF16(pf0, ones, lacc);
    lacc = MFMA_BF16(pf1, ones, lacc);

#pragma unroll
    for (int nt = 0; nt < 4; ++nt) {
      o[nt] = MFMA_BF16(pf0, vf[nt][0], o[nt]);
      o[nt] = MFMA_BF16(pf1, vf[nt][1], o[nt]);
    }
  }

  float inv[4];
#pragma unroll
  for (int r = 0; r < 4; ++r) inv[r] = 1.0f / lacc[r];
#pragma unroll
  for (int nt = 0; nt < 4; ++nt)
#pragma unroll
    for (int r = 0; r < 4; ++r) {
      const int gq = q0 + wave * 16 + quad * 4 + r;
      ctx[(size_t)(bb * Lseq + gq) * Dmod + h * HDim + nt * 16 + l16] =
          (bf16_t)(o[nt][r] * inv[r]);
    }
}

// ---------------------------------------------------------------------------
// out_kernel: OUT = CTX @ Wout^T. 128x64 tile, single-buffered LDS DMA,
// grid (x=m, y=n) for XCD locality on the CTX panel. fp32 out.
// ---------------------------------------------------------------------------
__global__ __launch_bounds__(256) void out_kernel(
    const bf16_t* __restrict__ Actx, const bf16_t* __restrict__ Bwout,
    float* __restrict__ out)
{
  __shared__ __align__(16) bf16_t As[128 * 64];
  __shared__ __align__(16) bf16_t Bs[64 * 64];

  const int tid  = threadIdx.x;
  const int wave = tid >> 6;
  const int lane = tid & 63;
  const int quad = lane >> 4;
  const int l16  = lane & 15;
  const int wm   = (wave & 1) * 64;
  const int wn   = (wave >> 1) * 32;
  const int m0   = blockIdx.x * 128;   // x = m: same-A blocks -> same XCD
  const int n0   = blockIdx.y * 64;

  const int srow8  = lane >> 3;
  const int schunk = (lane & 7) ^ srow8;

  f32x4 acc[4][2];
#pragma unroll
  for (int i = 0; i < 4; ++i)
#pragma unroll
    for (int j = 0; j < 2; ++j)
#pragma unroll
      for (int e = 0; e < 4; ++e) acc[i][j][e] = 0.0f;

  for (int kt = 0; kt < 16; ++kt) {
    const int k0 = kt * 64;
    __syncthreads();
#pragma unroll
    for (int i = 0; i < 4; ++i) {
      const int rb = wave * 32 + i * 8;
      async_ld16(&Actx[(size_t)(m0 + rb + srow8) * Dmod + k0 + schunk * 8], &As[rb * 64]);
    }
#pragma unroll
    for (int i = 0; i < 2; ++i) {
      const int rb = wave * 16 + i * 8;
      async_ld16(&Bwout[(size_t)(n0 + rb + srow8) * Dmod + k0 + schunk * 8], &Bs[rb * 64]);
    }
    __syncthreads();

    bf16x8 af[4][2], bfr[2][2];
#pragma unroll
    for (int mt = 0; mt < 4; ++mt) {
      const int row = wm + mt * 16 + l16;
      af[mt][0] = *(const bf16x8*)&As[swz(row, quad)];
      af[mt][1] = *(const bf16x8*)&As[swz(row, quad + 4)];
    }
#pragma unroll
    for (int nt = 0; nt < 2; ++nt) {
      const int row = wn + nt * 16 + l16;
      bfr[nt][0] = *(const bf16x8*)&Bs[swz(row, quad)];
      bfr[nt][1] = *(const bf16x8*)&Bs[swz(row, quad + 4)];
    }
#pragma unroll
    for (int mt = 0; mt < 4; ++mt)
#pragma unroll
      for (int nt = 0; nt < 2; ++nt) {
        acc[mt][nt] = MFMA_BF16(af[mt][0], bfr[nt][0], acc[mt][nt]);
        acc[mt][nt] = MFMA_BF16(af[mt][1], bfr[nt][1], acc[mt][nt]);
      }
  }

#pragma unroll
  for (int mt = 0; mt < 4; ++mt) {
    const int grb = m0 + wm + mt * 16 + quad * 4;
#pragma unroll
    for (int nt = 0; nt < 2; ++nt) {
      const int gc = n0 + wn + nt * 16 + l16;
#pragma unroll
      for (int r = 0; r < 4; ++r)
        out[(size_t)(grb + r) * Dmod + gc] = acc[mt][nt][r];
    }
  }
}

// ---------------------------------------------------------------------------
extern "C" void kernel_launch(void* const* d_in, const int* in_sizes, int n_in,
                              void* d_out, int out_size, void* d_ws, size_t ws_size,
                              hipStream_t stream) {
  (void)in_sizes; (void)n_in; (void)out_size; (void)ws_size;
  const float* Q    = (const float*)d_in[0];
  const float* K    = (const float*)d_in[1];
  const float* V    = (const float*)d_in[2];
  const float* wq   = (const float*)d_in[5];
  const float* wk   = (const float*)d_in[6];
  const float* wv   = (const float*)d_in[7];
  const float* wout = (const float*)d_in[8];
  float* out = (float*)d_out;

  bf16_t* wsb = (bf16_t*)d_ws;
  bf16_t* Qbf   = wsb;
  bf16_t* Kbf   = wsb + 4 * M1;
  bf16_t* Vbf   = wsb + 8 * M1;
  bf16_t* wqb   = wsb + 12 * M1;
  bf16_t* wkb   = wsb + 13 * M1;
  bf16_t* wvb   = wsb + 14 * M1;
  bf16_t* woutb = wsb + 15 * M1;
  bf16_t* qp    = wsb + 16 * M1;
  bf16_t* kp    = wsb + 20 * M1;
  bf16_t* vp    = wsb + 24 * M1;
  bf16_t* cws   = wsb;  // ctx reuses Qbf region (Qbf dead after proj)

  cvt_kernel<<<dim3(512, 1, 16), 256, 0, stream>>>(Q, K, V, wq, wk, wv, wout, wsb);
  proj_kernel<<<dim3(32, 16, 3), 256, 0, stream>>>(Qbf, Kbf, Vbf, wqb, wkb, wvb, qp, kp, vp);
  attn_kernel<<<dim3(32, 32), 256, 0, stream>>>(qp, kp, vp, cws);
  out_kernel<<<dim3(32, 16), 256, 0, stream>>>(cws, woutb, out);
}

// Round 13
// 207.360 us; speedup vs baseline: 1.5345x; 1.5345x over previous
//
#include <hip/hip_runtime.h>
#include <stdint.h>
#include <stddef.h>

typedef __bf16 bf16_t;
typedef bf16_t bf16x4 __attribute__((ext_vector_type(4)));
typedef bf16_t bf16x8 __attribute__((ext_vector_type(8)));
typedef float f32x4 __attribute__((ext_vector_type(4)));

#define MFMA_BF16(A_, B_, C_) __builtin_amdgcn_mfma_f32_16x16x32_bf16(A_, B_, C_, 0, 0, 0)

static constexpr int Lseq = 2048;
static constexpr int Dmod = 1024;
static constexpr int Hn   = 16;
static constexpr int HDim = 64;
static constexpr size_t M1 = 1u << 20;  // 1M elements

// XOR-swizzled offset (elements) into a [rows][64] bf16 tile, 16B chunks
__device__ __forceinline__ int swz(int row, int chunk) {
  return row * 64 + ((chunk ^ (row & 7)) << 3);
}

// async global->LDS DMA, 16B per lane, wave-uniform LDS base
__device__ __forceinline__ void async_ld16(const bf16_t* g, bf16_t* l) {
  __builtin_amdgcn_global_load_lds(
      (const __attribute__((address_space(1))) void*)g,
      (__attribute__((address_space(3))) void*)l, 16, 0, 0);
}

// ---------------------------------------------------------------------------
// cvt_kernel: fp32 -> bf16, 16B stores. wq additionally pre-scaled by
// 0.125*log2(e) so attention scores arrive ready for exp2 (no per-elem mul).
// ---------------------------------------------------------------------------
__global__ __launch_bounds__(256) void cvt_kernel(
    const float* __restrict__ Q, const float* __restrict__ K,
    const float* __restrict__ V, const float* __restrict__ wq,
    const float* __restrict__ wk, const float* __restrict__ wv,
    const float* __restrict__ wout, bf16_t* __restrict__ wsb)
{
  const int s = blockIdx.z;
  const float* __restrict__ src;
  if      (s < 4)   src = Q    + (size_t)s * M1;
  else if (s < 8)   src = K    + (size_t)(s - 4) * M1;
  else if (s < 12)  src = V    + (size_t)(s - 8) * M1;
  else if (s == 12) src = wq;
  else if (s == 13) src = wk;
  else if (s == 14) src = wv;
  else              src = wout;
  bf16_t* __restrict__ dst = wsb + (size_t)s * M1;
  const float scale = (s == 12) ? 0.18033688f : 1.0f;  // 0.125 * log2(e)

  const int idx = blockIdx.x * 256 + threadIdx.x;  // 0..131071 (1M/8)
  float4 a = ((const float4*)src)[idx * 2];
  float4 b = ((const float4*)src)[idx * 2 + 1];
  bf16x8 o;
  o[0] = (bf16_t)(a.x * scale); o[1] = (bf16_t)(a.y * scale);
  o[2] = (bf16_t)(a.z * scale); o[3] = (bf16_t)(a.w * scale);
  o[4] = (bf16_t)(b.x * scale); o[5] = (bf16_t)(b.y * scale);
  o[6] = (bf16_t)(b.z * scale); o[7] = (bf16_t)(b.w * scale);
  ((bf16x8*)dst)[idx] = o;
}

// ---------------------------------------------------------------------------
// proj_kernel: all-bf16 GEMM P = X @ W^T. 128(M)x64(N) tile, BK=64,
// single-buffered LDS DMA. Grid (x=m, y=n, z): XCD = m%8 locality.
//   z=0 -> q [B,H,L,HD]; z=1 -> k [B,H,L,HD]; z=2 -> v [B,H,HD,L]
// ---------------------------------------------------------------------------
__global__ __launch_bounds__(256) void proj_kernel(
    const bf16_t* __restrict__ Qbf, const bf16_t* __restrict__ Kbf,
    const bf16_t* __restrict__ Vbf, const bf16_t* __restrict__ wqb,
    const bf16_t* __restrict__ wkb, const bf16_t* __restrict__ wvb,
    bf16_t* __restrict__ qo, bf16_t* __restrict__ ko, bf16_t* __restrict__ vo)
{
  const int z = blockIdx.z;
  const bf16_t* __restrict__ A  = (z == 0) ? Qbf : (z == 1) ? Kbf : Vbf;
  const bf16_t* __restrict__ Bw = (z == 0) ? wqb : (z == 1) ? wkb : wvb;
  bf16_t* __restrict__ dst      = (z == 0) ? qo  : (z == 1) ? ko  : vo;

  __shared__ __align__(16) bf16_t As[128 * 64];  // 16 KB
  __shared__ __align__(16) bf16_t Bs[64 * 64];   //  8 KB

  const int tid  = threadIdx.x;
  const int wave = tid >> 6;
  const int lane = tid & 63;
  const int quad = lane >> 4;
  const int l16  = lane & 15;
  const int wm   = (wave & 1) * 64;
  const int wn   = (wave >> 1) * 32;
  const int m0   = blockIdx.x * 128;   // x = m (32): same-A blocks -> same XCD
  const int n0   = blockIdx.y * 64;    // y = n (16)

  const int srow8  = lane >> 3;
  const int schunk = (lane & 7) ^ srow8;

  f32x4 acc[4][2];
#pragma unroll
  for (int i = 0; i < 4; ++i)
#pragma unroll
    for (int j = 0; j < 2; ++j)
#pragma unroll
      for (int e = 0; e < 4; ++e) acc[i][j][e] = 0.0f;

  for (int kt = 0; kt < 16; ++kt) {
    const int k0 = kt * 64;
    __syncthreads();  // LDS reads of previous iter done
#pragma unroll
    for (int i = 0; i < 4; ++i) {
      const int rb = wave * 32 + i * 8;
      async_ld16(&A[(size_t)(m0 + rb + srow8) * Dmod + k0 + schunk * 8], &As[rb * 64]);
    }
#pragma unroll
    for (int i = 0; i < 2; ++i) {
      const int rb = wave * 16 + i * 8;
      async_ld16(&Bw[(size_t)(n0 + rb + srow8) * Dmod + k0 + schunk * 8], &Bs[rb * 64]);
    }
    __syncthreads();  // DMA drained

    bf16x8 af[4][2], bfr[2][2];
#pragma unroll
    for (int mt = 0; mt < 4; ++mt) {
      const int row = wm + mt * 16 + l16;
      af[mt][0] = *(const bf16x8*)&As[swz(row, quad)];
      af[mt][1] = *(const bf16x8*)&As[swz(row, quad + 4)];
    }
#pragma unroll
    for (int nt = 0; nt < 2; ++nt) {
      const int row = wn + nt * 16 + l16;
      bfr[nt][0] = *(const bf16x8*)&Bs[swz(row, quad)];
      bfr[nt][1] = *(const bf16x8*)&Bs[swz(row, quad + 4)];
    }
#pragma unroll
    for (int mt = 0; mt < 4; ++mt)
#pragma unroll
      for (int nt = 0; nt < 2; ++nt) {
        acc[mt][nt] = MFMA_BF16(af[mt][0], bfr[nt][0], acc[mt][nt]);
        acc[mt][nt] = MFMA_BF16(af[mt][1], bfr[nt][1], acc[mt][nt]);
      }
  }

#pragma unroll
  for (int mt = 0; mt < 4; ++mt) {
    const int grb = m0 + wm + mt * 16 + quad * 4;
    const int bb  = grb >> 11;
    const int lb  = grb & 2047;
#pragma unroll
    for (int nt = 0; nt < 2; ++nt) {
      const int gc = n0 + wn + nt * 16 + l16;
      const int h  = gc >> 6;
      const int hd = gc & 63;
      if (z == 2) {
        bf16x4 pk;
#pragma unroll
        for (int r = 0; r < 4; ++r) pk[r] = (bf16_t)acc[mt][nt][r];
        *(bf16x4*)&dst[(((size_t)(bb * Hn + h) * HDim + hd) << 11) + lb] = pk;
      } else {
#pragma unroll
        for (int r = 0; r < 4; ++r)
          dst[(((size_t)(bb * Hn + h) * Lseq + lb + r) << 6) + hd] = (bf16_t)acc[mt][nt][r];
      }
    }
  }
}

// ---------------------------------------------------------------------------
// attn_kernel: causal flash attention — R9 configuration (best measured:
// 40.3 us): 256 thr = 4 waves x 16 q-rows, one 64-row q-tile per block,
// grid (x=32 bh -> XCD=bh%8, y=32 qt LPT), single-buffered K/V DMA (25.6 KB
// LDS, 6 blocks/CU capacity). Micro-opts vs R9: wave-uniform diag branch
// (mask VALU only on the 1-of-~17 diagonal iteration), strength-reduced DMA
// pointers, hoisted swizzled LDS read offsets.
// ---------------------------------------------------------------------------
__global__ __launch_bounds__(256) void attn_kernel(
    const bf16_t* __restrict__ q, const bf16_t* __restrict__ k,
    const bf16_t* __restrict__ v, bf16_t* __restrict__ ctx)
{
  const int bh = blockIdx.x;            // 0..31  (fast dim -> XCD = bh%8)
  const int qt = 31 - blockIdx.y;       // LPT: longest blocks first
  const int bb = bh >> 4;
  const int h  = bh & 15;
  const int q0 = qt * 64;

  const int tid  = threadIdx.x;
  const int wave = tid >> 6;
  const int lane = tid & 63;
  const int quad = lane >> 4;
  const int l16  = lane & 15;

  __shared__ __align__(16) bf16_t Ks[64 * 64];   // 8 KB
  __shared__ __align__(16) bf16_t Vs[64 * 64];   // 8 KB
  __shared__ __align__(16) bf16_t Ps[4][16][72]; // 9 KB

  const bf16_t* __restrict__ qb = q + (size_t)bh * (Lseq * HDim);
  const bf16_t* __restrict__ kb = k + (size_t)bh * (Lseq * HDim);
  const bf16_t* __restrict__ vb = v + (size_t)bh * (HDim * Lseq);

  const int srow8  = lane >> 3;
  const int schunk = (lane & 7) ^ srow8;

  bf16x8 ones;
#pragma unroll
  for (int i = 0; i < 8; ++i) ones[i] = (bf16_t)1.0f;

  const int qrow = q0 + wave * 16 + l16;
  bf16x8 qf0 = *(const bf16x8*)&qb[(size_t)qrow * HDim + quad * 8];
  bf16x8 qf1 = *(const bf16x8*)&qb[(size_t)qrow * HDim + 32 + quad * 8];

  // strength-reduced per-lane DMA source pointers (advance per k-tile)
  const bf16_t* ks0 = kb + (size_t)(wave * 16 + srow8) * HDim + schunk * 8;
  const bf16_t* ks1 = ks0 + (size_t)8 * HDim;
  const bf16_t* vs0 = vb + (size_t)(wave * 16 + srow8) * Lseq + schunk * 8;
  const bf16_t* vs1 = vs0 + (size_t)8 * Lseq;
  bf16_t* ldk0 = &Ks[(wave * 16) * 64];
  bf16_t* ldk1 = &Ks[(wave * 16 + 8) * 64];
  bf16_t* ldv0 = &Vs[(wave * 16) * 64];
  bf16_t* ldv1 = &Vs[(wave * 16 + 8) * 64];

  // hoisted swizzled LDS read offsets (same rows for Ks and Vs)
  int ro0[4], ro1[4];
#pragma unroll
  for (int nt = 0; nt < 4; ++nt) {
    const int row = nt * 16 + l16;
    ro0[nt] = swz(row, quad);
    ro1[nt] = swz(row, quad + 4);
  }

  f32x4 o[4];
  f32x4 lacc;
#pragma unroll
  for (int e = 0; e < 4; ++e) lacc[e] = 0.0f;
#pragma unroll
  for (int nt = 0; nt < 4; ++nt)
#pragma unroll
    for (int e = 0; e < 4; ++e) o[nt][e] = 0.0f;

  for (int jt = 0; jt <= qt; ++jt) {
    __syncthreads();  // prior iter's LDS reads done
    async_ld16(ks0, ldk0);
    async_ld16(ks1, ldk1);
    async_ld16(vs0, ldv0);
    async_ld16(vs1, ldv1);
    ks0 += (size_t)64 * HDim; ks1 += (size_t)64 * HDim;
    vs0 += 64;                vs1 += 64;
    __syncthreads();  // DMA drained

    // S^T = K Q^T  (m=key, n=query); scores pre-scaled for exp2
    f32x4 s[4];
#pragma unroll
    for (int nt = 0; nt < 4; ++nt) {
#pragma unroll
      for (int e = 0; e < 4; ++e) s[nt][e] = 0.0f;
      bf16x8 kf0 = *(const bf16x8*)&Ks[ro0[nt]];
      bf16x8 kf1 = *(const bf16x8*)&Ks[ro1[nt]];
      s[nt] = MFMA_BF16(kf0, qf0, s[nt]);
      s[nt] = MFMA_BF16(kf1, qf1, s[nt]);
    }

    // exp2 (scale pre-folded into wq); wave-uniform branch: mask only on
    // the diagonal tile (1 of ~qt+1 iterations)
    if (jt == qt) {
#pragma unroll
      for (int nt = 0; nt < 4; ++nt) {
        bf16x4 pk;
#pragma unroll
        for (int r = 0; r < 4; ++r) {
          float val = s[nt][r];
          if (nt * 16 + quad * 4 + r > wave * 16 + l16) val = -1e30f;
          pk[r] = (bf16_t)__builtin_amdgcn_exp2f(val);
        }
        *(bf16x4*)&Ps[wave][l16][nt * 16 + quad * 4] = pk;
      }
    } else {
#pragma unroll
      for (int nt = 0; nt < 4; ++nt) {
        bf16x4 pk;
#pragma unroll
        for (int r = 0; r < 4; ++r)
          pk[r] = (bf16_t)__builtin_amdgcn_exp2f(s[nt][r]);
        *(bf16x4*)&Ps[wave][l16][nt * 16 + quad * 4] = pk;
      }
    }

    // P fragments (A-layout) — wave-local LDS round-trip
    bf16x8 pf0 = *(const bf16x8*)&Ps[wave][l16][quad * 8];
    bf16x8 pf1 = *(const bf16x8*)&Ps[wave][l16][32 + quad * 8];

    lacc = MFMA_BF16(pf0, ones, lacc);
    lacc = MFMA_BF16(pf1, ones, lacc);

#pragma unroll
    for (int nt = 0; nt < 4; ++nt) {
      bf16x8 vf0 = *(const bf16x8*)&Vs[ro0[nt]];
      bf16x8 vf1 = *(const bf16x8*)&Vs[ro1[nt]];
      o[nt] = MFMA_BF16(pf0, vf0, o[nt]);
      o[nt] = MFMA_BF16(pf1, vf1, o[nt]);
    }
  }

  float inv[4];
#pragma unroll
  for (int r = 0; r < 4; ++r) inv[r] = 1.0f / lacc[r];
#pragma unroll
  for (int nt = 0; nt < 4; ++nt)
#pragma unroll
    for (int r = 0; r < 4; ++r) {
      const int gq = q0 + wave * 16 + quad * 4 + r;
      ctx[(size_t)(bb * Lseq + gq) * Dmod + h * HDim + nt * 16 + l16] =
          (bf16_t)(o[nt][r] * inv[r]);
    }
}

// ---------------------------------------------------------------------------
// out_kernel: OUT = CTX @ Wout^T. 128x64 tile, single-buffered LDS DMA,
// grid (x=m, y=n) for XCD locality on the CTX panel. fp32 out.
// ---------------------------------------------------------------------------
__global__ __launch_bounds__(256) void out_kernel(
    const bf16_t* __restrict__ Actx, const bf16_t* __restrict__ Bwout,
    float* __restrict__ out)
{
  __shared__ __align__(16) bf16_t As[128 * 64];
  __shared__ __align__(16) bf16_t Bs[64 * 64];

  const int tid  = threadIdx.x;
  const int wave = tid >> 6;
  const int lane = tid & 63;
  const int quad = lane >> 4;
  const int l16  = lane & 15;
  const int wm   = (wave & 1) * 64;
  const int wn   = (wave >> 1) * 32;
  const int m0   = blockIdx.x * 128;   // x = m: same-A blocks -> same XCD
  const int n0   = blockIdx.y * 64;

  const int srow8  = lane >> 3;
  const int schunk = (lane & 7) ^ srow8;

  f32x4 acc[4][2];
#pragma unroll
  for (int i = 0; i < 4; ++i)
#pragma unroll
    for (int j = 0; j < 2; ++j)
#pragma unroll
      for (int e = 0; e < 4; ++e) acc[i][j][e] = 0.0f;

  for (int kt = 0; kt < 16; ++kt) {
    const int k0 = kt * 64;
    __syncthreads();
#pragma unroll
    for (int i = 0; i < 4; ++i) {
      const int rb = wave * 32 + i * 8;
      async_ld16(&Actx[(size_t)(m0 + rb + srow8) * Dmod + k0 + schunk * 8], &As[rb * 64]);
    }
#pragma unroll
    for (int i = 0; i < 2; ++i) {
      const int rb = wave * 16 + i * 8;
      async_ld16(&Bwout[(size_t)(n0 + rb + srow8) * Dmod + k0 + schunk * 8], &Bs[rb * 64]);
    }
    __syncthreads();

    bf16x8 af[4][2], bfr[2][2];
#pragma unroll
    for (int mt = 0; mt < 4; ++mt) {
      const int row = wm + mt * 16 + l16;
      af[mt][0] = *(const bf16x8*)&As[swz(row, quad)];
      af[mt][1] = *(const bf16x8*)&As[swz(row, quad + 4)];
    }
#pragma unroll
    for (int nt = 0; nt < 2; ++nt) {
      const int row = wn + nt * 16 + l16;
      bfr[nt][0] = *(const bf16x8*)&Bs[swz(row, quad)];
      bfr[nt][1] = *(const bf16x8*)&Bs[swz(row, quad + 4)];
    }
#pragma unroll
    for (int mt = 0; mt < 4; ++mt)
#pragma unroll
      for (int nt = 0; nt < 2; ++nt) {
        acc[mt][nt] = MFMA_BF16(af[mt][0], bfr[nt][0], acc[mt][nt]);
        acc[mt][nt] = MFMA_BF16(af[mt][1], bfr[nt][1], acc[mt][nt]);
      }
  }

#pragma unroll
  for (int mt = 0; mt < 4; ++mt) {
    const int grb = m0 + wm + mt * 16 + quad * 4;
#pragma unroll
    for (int nt = 0; nt < 2; ++nt) {
      const int gc = n0 + wn + nt * 16 + l16;
#pragma unroll
      for (int r = 0; r < 4; ++r)
        out[(size_t)(grb + r) * Dmod + gc] = acc[mt][nt][r];
    }
  }
}

// ---------------------------------------------------------------------------
extern "C" void kernel_launch(void* const* d_in, const int* in_sizes, int n_in,
                              void* d_out, int out_size, void* d_ws, size_t ws_size,
                              hipStream_t stream) {
  (void)in_sizes; (void)n_in; (void)out_size; (void)ws_size;
  const float* Q    = (const float*)d_in[0];
  const float* K    = (const float*)d_in[1];
  const float* V    = (const float*)d_in[2];
  const float* wq   = (const float*)d_in[5];
  const float* wk   = (const float*)d_in[6];
  const float* wv   = (const float*)d_in[7];
  const float* wout = (const float*)d_in[8];
  float* out = (float*)d_out;

  bf16_t* wsb = (bf16_t*)d_ws;
  bf16_t* Qbf   = wsb;
  bf16_t* Kbf   = wsb + 4 * M1;
  bf16_t* Vbf   = wsb + 8 * M1;
  bf16_t* wqb   = wsb + 12 * M1;
  bf16_t* wkb   = wsb + 13 * M1;
  bf16_t* wvb   = wsb + 14 * M1;
  bf16_t* woutb = wsb + 15 * M1;
  bf16_t* qp    = wsb + 16 * M1;
  bf16_t* kp    = wsb + 20 * M1;
  bf16_t* vp    = wsb + 24 * M1;
  bf16_t* cws   = wsb;  // ctx reuses Qbf region (Qbf dead after proj)

  cvt_kernel<<<dim3(512, 1, 16), 256, 0, stream>>>(Q, K, V, wq, wk, wv, wout, wsb);
  proj_kernel<<<dim3(32, 16, 3), 256, 0, stream>>>(Qbf, Kbf, Vbf, wqb, wkb, wvb, qp, kp, vp);
  attn_kernel<<<dim3(32, 32), 256, 0, stream>>>(qp, kp, vp, cws);
  out_kernel<<<dim3(32, 16), 256, 0, stream>>>(cws, woutb, out);
}

// Round 14
// 204.654 us; speedup vs baseline: 1.5548x; 1.0132x over previous
//
#include <hip/hip_runtime.h>
#include <stdint.h>
#include <stddef.h>

typedef __bf16 bf16_t;
typedef bf16_t bf16x4 __attribute__((ext_vector_type(4)));
typedef bf16_t bf16x8 __attribute__((ext_vector_type(8)));
typedef float f32x4 __attribute__((ext_vector_type(4)));

#define MFMA_BF16(A_, B_, C_) __builtin_amdgcn_mfma_f32_16x16x32_bf16(A_, B_, C_, 0, 0, 0)

static constexpr int Lseq = 2048;
static constexpr int Dmod = 1024;
static constexpr int Hn   = 16;
static constexpr int HDim = 64;
static constexpr size_t M1 = 1u << 20;  // 1M elements

// XOR-swizzled offset (elements) into a [rows][64] bf16 tile, 16B chunks
__device__ __forceinline__ int swz(int row, int chunk) {
  return row * 64 + ((chunk ^ (row & 7)) << 3);
}

// async global->LDS DMA, 16B per lane, wave-uniform LDS base
__device__ __forceinline__ void async_ld16(const bf16_t* g, bf16_t* l) {
  __builtin_amdgcn_global_load_lds(
      (const __attribute__((address_space(1))) void*)g,
      (__attribute__((address_space(3))) void*)l, 16, 0, 0);
}

// ---------------------------------------------------------------------------
// cvt_kernel: fp32 -> bf16, 16B stores. wq additionally pre-scaled by
// 0.125*log2(e) so attention scores arrive ready for exp2 (no per-elem mul).
// ---------------------------------------------------------------------------
__global__ __launch_bounds__(256) void cvt_kernel(
    const float* __restrict__ Q, const float* __restrict__ K,
    const float* __restrict__ V, const float* __restrict__ wq,
    const float* __restrict__ wk, const float* __restrict__ wv,
    const float* __restrict__ wout, bf16_t* __restrict__ wsb)
{
  const int s = blockIdx.z;
  const float* __restrict__ src;
  if      (s < 4)   src = Q    + (size_t)s * M1;
  else if (s < 8)   src = K    + (size_t)(s - 4) * M1;
  else if (s < 12)  src = V    + (size_t)(s - 8) * M1;
  else if (s == 12) src = wq;
  else if (s == 13) src = wk;
  else if (s == 14) src = wv;
  else              src = wout;
  bf16_t* __restrict__ dst = wsb + (size_t)s * M1;
  const float scale = (s == 12) ? 0.18033688f : 1.0f;  // 0.125 * log2(e)

  const int idx = blockIdx.x * 256 + threadIdx.x;  // 0..131071 (1M/8)
  float4 a = ((const float4*)src)[idx * 2];
  float4 b = ((const float4*)src)[idx * 2 + 1];
  bf16x8 o;
  o[0] = (bf16_t)(a.x * scale); o[1] = (bf16_t)(a.y * scale);
  o[2] = (bf16_t)(a.z * scale); o[3] = (bf16_t)(a.w * scale);
  o[4] = (bf16_t)(b.x * scale); o[5] = (bf16_t)(b.y * scale);
  o[6] = (bf16_t)(b.z * scale); o[7] = (bf16_t)(b.w * scale);
  ((bf16x8*)dst)[idx] = o;
}

// ---------------------------------------------------------------------------
// proj_kernel: all-bf16 GEMM P = X @ W^T. 128(M)x64(N) tile, BK=64,
// single-buffered LDS DMA. Grid (x=m, y=n, z): XCD = m%8 locality.
//   z=0 -> q [B,H,L,HD]; z=1 -> k [B,H,L,HD]; z=2 -> v [B,H,HD,L]
// ---------------------------------------------------------------------------
__global__ __launch_bounds__(256) void proj_kernel(
    const bf16_t* __restrict__ Qbf, const bf16_t* __restrict__ Kbf,
    const bf16_t* __restrict__ Vbf, const bf16_t* __restrict__ wqb,
    const bf16_t* __restrict__ wkb, const bf16_t* __restrict__ wvb,
    bf16_t* __restrict__ qo, bf16_t* __restrict__ ko, bf16_t* __restrict__ vo)
{
  const int z = blockIdx.z;
  const bf16_t* __restrict__ A  = (z == 0) ? Qbf : (z == 1) ? Kbf : Vbf;
  const bf16_t* __restrict__ Bw = (z == 0) ? wqb : (z == 1) ? wkb : wvb;
  bf16_t* __restrict__ dst      = (z == 0) ? qo  : (z == 1) ? ko  : vo;

  __shared__ __align__(16) bf16_t As[128 * 64];  // 16 KB
  __shared__ __align__(16) bf16_t Bs[64 * 64];   //  8 KB

  const int tid  = threadIdx.x;
  const int wave = tid >> 6;
  const int lane = tid & 63;
  const int quad = lane >> 4;
  const int l16  = lane & 15;
  const int wm   = (wave & 1) * 64;
  const int wn   = (wave >> 1) * 32;
  const int m0   = blockIdx.x * 128;   // x = m (32): same-A blocks -> same XCD
  const int n0   = blockIdx.y * 64;    // y = n (16)

  const int srow8  = lane >> 3;
  const int schunk = (lane & 7) ^ srow8;

  f32x4 acc[4][2];
#pragma unroll
  for (int i = 0; i < 4; ++i)
#pragma unroll
    for (int j = 0; j < 2; ++j)
#pragma unroll
      for (int e = 0; e < 4; ++e) acc[i][j][e] = 0.0f;

  for (int kt = 0; kt < 16; ++kt) {
    const int k0 = kt * 64;
    __syncthreads();  // LDS reads of previous iter done
#pragma unroll
    for (int i = 0; i < 4; ++i) {
      const int rb = wave * 32 + i * 8;
      async_ld16(&A[(size_t)(m0 + rb + srow8) * Dmod + k0 + schunk * 8], &As[rb * 64]);
    }
#pragma unroll
    for (int i = 0; i < 2; ++i) {
      const int rb = wave * 16 + i * 8;
      async_ld16(&Bw[(size_t)(n0 + rb + srow8) * Dmod + k0 + schunk * 8], &Bs[rb * 64]);
    }
    __syncthreads();  // DMA drained

    bf16x8 af[4][2], bfr[2][2];
#pragma unroll
    for (int mt = 0; mt < 4; ++mt) {
      const int row = wm + mt * 16 + l16;
      af[mt][0] = *(const bf16x8*)&As[swz(row, quad)];
      af[mt][1] = *(const bf16x8*)&As[swz(row, quad + 4)];
    }
#pragma unroll
    for (int nt = 0; nt < 2; ++nt) {
      const int row = wn + nt * 16 + l16;
      bfr[nt][0] = *(const bf16x8*)&Bs[swz(row, quad)];
      bfr[nt][1] = *(const bf16x8*)&Bs[swz(row, quad + 4)];
    }
#pragma unroll
    for (int mt = 0; mt < 4; ++mt)
#pragma unroll
      for (int nt = 0; nt < 2; ++nt) {
        acc[mt][nt] = MFMA_BF16(af[mt][0], bfr[nt][0], acc[mt][nt]);
        acc[mt][nt] = MFMA_BF16(af[mt][1], bfr[nt][1], acc[mt][nt]);
      }
  }

#pragma unroll
  for (int mt = 0; mt < 4; ++mt) {
    const int grb = m0 + wm + mt * 16 + quad * 4;
    const int bb  = grb >> 11;
    const int lb  = grb & 2047;
#pragma unroll
    for (int nt = 0; nt < 2; ++nt) {
      const int gc = n0 + wn + nt * 16 + l16;
      const int h  = gc >> 6;
      const int hd = gc & 63;
      if (z == 2) {
        bf16x4 pk;
#pragma unroll
        for (int r = 0; r < 4; ++r) pk[r] = (bf16_t)acc[mt][nt][r];
        *(bf16x4*)&dst[(((size_t)(bb * Hn + h) * HDim + hd) << 11) + lb] = pk;
      } else {
#pragma unroll
        for (int r = 0; r < 4; ++r)
          dst[(((size_t)(bb * Hn + h) * Lseq + lb + r) << 6) + hd] = (bf16_t)acc[mt][nt][r];
      }
    }
  }
}

// ---------------------------------------------------------------------------
// attn_kernel: causal flash attention — R13 config (4 waves x 16 q-rows,
// 1024 blocks, LPT, XCD=bh%8) + DOUBLE-BUFFERED K/V DMA: one barrier per
// k-tile, next tile's DMA in flight under current tile's compute (the
// single-buffered version exposed the full drain between its 2 barriers).
// LDS 41.2 KB -> 3 blocks/CU. Wave-uniform diag branch; strength-reduced
// pointers; hoisted swizzled read offsets.
// ---------------------------------------------------------------------------
__global__ __launch_bounds__(256) void attn_kernel(
    const bf16_t* __restrict__ q, const bf16_t* __restrict__ k,
    const bf16_t* __restrict__ v, bf16_t* __restrict__ ctx)
{
  const int bh = blockIdx.x;            // 0..31  (fast dim -> XCD = bh%8)
  const int qt = 31 - blockIdx.y;       // LPT: longest blocks first
  const int bb = bh >> 4;
  const int h  = bh & 15;
  const int q0 = qt * 64;

  const int tid  = threadIdx.x;
  const int wave = tid >> 6;
  const int lane = tid & 63;
  const int quad = lane >> 4;
  const int l16  = lane & 15;

  __shared__ __align__(16) bf16_t Ks[2][64 * 64];  // 16 KB
  __shared__ __align__(16) bf16_t Vs[2][64 * 64];  // 16 KB
  __shared__ __align__(16) bf16_t Ps[4][16][72];   //  9 KB

  const bf16_t* __restrict__ qb = q + (size_t)bh * (Lseq * HDim);
  const bf16_t* __restrict__ kb = k + (size_t)bh * (Lseq * HDim);
  const bf16_t* __restrict__ vb = v + (size_t)bh * (HDim * Lseq);

  const int srow8  = lane >> 3;
  const int schunk = (lane & 7) ^ srow8;

  bf16x8 ones;
#pragma unroll
  for (int i = 0; i < 8; ++i) ones[i] = (bf16_t)1.0f;

  const int qrow = q0 + wave * 16 + l16;
  bf16x8 qf0 = *(const bf16x8*)&qb[(size_t)qrow * HDim + quad * 8];
  bf16x8 qf1 = *(const bf16x8*)&qb[(size_t)qrow * HDim + 32 + quad * 8];

  // strength-reduced per-lane DMA source pointers (advance per k-tile)
  const bf16_t* ks0 = kb + (size_t)(wave * 16 + srow8) * HDim + schunk * 8;
  const bf16_t* ks1 = ks0 + (size_t)8 * HDim;
  const bf16_t* vs0 = vb + (size_t)(wave * 16 + srow8) * Lseq + schunk * 8;
  const bf16_t* vs1 = vs0 + (size_t)8 * Lseq;
  const int ldo0 = (wave * 16) * 64;
  const int ldo1 = (wave * 16 + 8) * 64;

  // hoisted swizzled LDS read offsets (same rows for Ks and Vs)
  int ro0[4], ro1[4];
#pragma unroll
  for (int nt = 0; nt < 4; ++nt) {
    const int row = nt * 16 + l16;
    ro0[nt] = swz(row, quad);
    ro1[nt] = swz(row, quad + 4);
  }

  f32x4 o[4];
  f32x4 lacc;
#pragma unroll
  for (int e = 0; e < 4; ++e) lacc[e] = 0.0f;
#pragma unroll
  for (int nt = 0; nt < 4; ++nt)
#pragma unroll
    for (int e = 0; e < 4; ++e) o[nt][e] = 0.0f;

  // preload tile jt=0 into buffer 0
  async_ld16(ks0, &Ks[0][ldo0]);
  async_ld16(ks1, &Ks[0][ldo1]);
  async_ld16(vs0, &Vs[0][ldo0]);
  async_ld16(vs1, &Vs[0][ldo1]);
  ks0 += (size_t)64 * HDim; ks1 += (size_t)64 * HDim;
  vs0 += 64;                vs1 += 64;

  for (int jt = 0; jt <= qt; ++jt) {
    const int cur = jt & 1;
    __syncthreads();  // drains cur's DMA (issuer waits vmcnt before barrier)
                      // and guarantees alt's readers (iter jt-1) are done

    if (jt < qt) {    // prefetch next tile into alt; in flight under compute
      async_ld16(ks0, &Ks[cur ^ 1][ldo0]);
      async_ld16(ks1, &Ks[cur ^ 1][ldo1]);
      async_ld16(vs0, &Vs[cur ^ 1][ldo0]);
      async_ld16(vs1, &Vs[cur ^ 1][ldo1]);
      ks0 += (size_t)64 * HDim; ks1 += (size_t)64 * HDim;
      vs0 += 64;                vs1 += 64;
    }

    // S^T = K Q^T  (m=key, n=query); scores pre-scaled for exp2
    f32x4 s[4];
#pragma unroll
    for (int nt = 0; nt < 4; ++nt) {
#pragma unroll
      for (int e = 0; e < 4; ++e) s[nt][e] = 0.0f;
      bf16x8 kf0 = *(const bf16x8*)&Ks[cur][ro0[nt]];
      bf16x8 kf1 = *(const bf16x8*)&Ks[cur][ro1[nt]];
      s[nt] = MFMA_BF16(kf0, qf0, s[nt]);
      s[nt] = MFMA_BF16(kf1, qf1, s[nt]);
    }

    // exp2 (scale pre-folded); wave-uniform diagonal branch
    if (jt == qt) {
#pragma unroll
      for (int nt = 0; nt < 4; ++nt) {
        bf16x4 pk;
#pragma unroll
        for (int r = 0; r < 4; ++r) {
          float val = s[nt][r];
          if (nt * 16 + quad * 4 + r > wave * 16 + l16) val = -1e30f;
          pk[r] = (bf16_t)__builtin_amdgcn_exp2f(val);
        }
        *(bf16x4*)&Ps[wave][l16][nt * 16 + quad * 4] = pk;
      }
    } else {
#pragma unroll
      for (int nt = 0; nt < 4; ++nt) {
        bf16x4 pk;
#pragma unroll
        for (int r = 0; r < 4; ++r)
          pk[r] = (bf16_t)__builtin_amdgcn_exp2f(s[nt][r]);
        *(bf16x4*)&Ps[wave][l16][nt * 16 + quad * 4] = pk;
      }
    }

    // P fragments (A-layout) — wave-local LDS round-trip
    bf16x8 pf0 = *(const bf16x8*)&Ps[wave][l16][quad * 8];
    bf16x8 pf1 = *(const bf16x8*)&Ps[wave][l16][32 + quad * 8];

    lacc = MFMA_BF16(pf0, ones, lacc);
    lacc = MFMA_BF16(pf1, ones, lacc);

#pragma unroll
    for (int nt = 0; nt < 4; ++nt) {
      bf16x8 vf0 = *(const bf16x8*)&Vs[cur][ro0[nt]];
      bf16x8 vf1 = *(const bf16x8*)&Vs[cur][ro1[nt]];
      o[nt] = MFMA_BF16(pf0, vf0, o[nt]);
      o[nt] = MFMA_BF16(pf1, vf1, o[nt]);
    }
  }

  float inv[4];
#pragma unroll
  for (int r = 0; r < 4; ++r) inv[r] = 1.0f / lacc[r];
#pragma unroll
  for (int nt = 0; nt < 4; ++nt)
#pragma unroll
    for (int r = 0; r < 4; ++r) {
      const int gq = q0 + wave * 16 + quad * 4 + r;
      ctx[(size_t)(bb * Lseq + gq) * Dmod + h * HDim + nt * 16 + l16] =
          (bf16_t)(o[nt][r] * inv[r]);
    }
}

// ---------------------------------------------------------------------------
// out_kernel: OUT = CTX @ Wout^T. 128x64 tile, single-buffered LDS DMA,
// grid (x=m, y=n) for XCD locality on the CTX panel. fp32 out.
// ---------------------------------------------------------------------------
__global__ __launch_bounds__(256) void out_kernel(
    const bf16_t* __restrict__ Actx, const bf16_t* __restrict__ Bwout,
    float* __restrict__ out)
{
  __shared__ __align__(16) bf16_t As[128 * 64];
  __shared__ __align__(16) bf16_t Bs[64 * 64];

  const int tid  = threadIdx.x;
  const int wave = tid >> 6;
  const int lane = tid & 63;
  const int quad = lane >> 4;
  const int l16  = lane & 15;
  const int wm   = (wave & 1) * 64;
  const int wn   = (wave >> 1) * 32;
  const int m0   = blockIdx.x * 128;   // x = m: same-A blocks -> same XCD
  const int n0   = blockIdx.y * 64;

  const int srow8  = lane >> 3;
  const int schunk = (lane & 7) ^ srow8;

  f32x4 acc[4][2];
#pragma unroll
  for (int i = 0; i < 4; ++i)
#pragma unroll
    for (int j = 0; j < 2; ++j)
#pragma unroll
      for (int e = 0; e < 4; ++e) acc[i][j][e] = 0.0f;

  for (int kt = 0; kt < 16; ++kt) {
    const int k0 = kt * 64;
    __syncthreads();
#pragma unroll
    for (int i = 0; i < 4; ++i) {
      const int rb = wave * 32 + i * 8;
      async_ld16(&Actx[(size_t)(m0 + rb + srow8) * Dmod + k0 + schunk * 8], &As[rb * 64]);
    }
#pragma unroll
    for (int i = 0; i < 2; ++i) {
      const int rb = wave * 16 + i * 8;
      async_ld16(&Bwout[(size_t)(n0 + rb + srow8) * Dmod + k0 + schunk * 8], &Bs[rb * 64]);
    }
    __syncthreads();

    bf16x8 af[4][2], bfr[2][2];
#pragma unroll
    for (int mt = 0; mt < 4; ++mt) {
      const int row = wm + mt * 16 + l16;
      af[mt][0] = *(const bf16x8*)&As[swz(row, quad)];
      af[mt][1] = *(const bf16x8*)&As[swz(row, quad + 4)];
    }
#pragma unroll
    for (int nt = 0; nt < 2; ++nt) {
      const int row = wn + nt * 16 + l16;
      bfr[nt][0] = *(const bf16x8*)&Bs[swz(row, quad)];
      bfr[nt][1] = *(const bf16x8*)&Bs[swz(row, quad + 4)];
    }
#pragma unroll
    for (int mt = 0; mt < 4; ++mt)
#pragma unroll
      for (int nt = 0; nt < 2; ++nt) {
        acc[mt][nt] = MFMA_BF16(af[mt][0], bfr[nt][0], acc[mt][nt]);
        acc[mt][nt] = MFMA_BF16(af[mt][1], bfr[nt][1], acc[mt][nt]);
      }
  }

#pragma unroll
  for (int mt = 0; mt < 4; ++mt) {
    const int grb = m0 + wm + mt * 16 + quad * 4;
#pragma unroll
    for (int nt = 0; nt < 2; ++nt) {
      const int gc = n0 + wn + nt * 16 + l16;
#pragma unroll
      for (int r = 0; r < 4; ++r)
        out[(size_t)(grb + r) * Dmod + gc] = acc[mt][nt][r];
    }
  }
}

// ---------------------------------------------------------------------------
extern "C" void kernel_launch(void* const* d_in, const int* in_sizes, int n_in,
                              void* d_out, int out_size, void* d_ws, size_t ws_size,
                              hipStream_t stream) {
  (void)in_sizes; (void)n_in; (void)out_size; (void)ws_size;
  const float* Q    = (const float*)d_in[0];
  const float* K    = (const float*)d_in[1];
  const float* V    = (const float*)d_in[2];
  const float* wq   = (const float*)d_in[5];
  const float* wk   = (const float*)d_in[6];
  const float* wv   = (const float*)d_in[7];
  const float* wout = (const float*)d_in[8];
  float* out = (float*)d_out;

  bf16_t* wsb = (bf16_t*)d_ws;
  bf16_t* Qbf   = wsb;
  bf16_t* Kbf   = wsb + 4 * M1;
  bf16_t* Vbf   = wsb + 8 * M1;
  bf16_t* wqb   = wsb + 12 * M1;
  bf16_t* wkb   = wsb + 13 * M1;
  bf16_t* wvb   = wsb + 14 * M1;
  bf16_t* woutb = wsb + 15 * M1;
  bf16_t* qp    = wsb + 16 * M1;
  bf16_t* kp    = wsb + 20 * M1;
  bf16_t* vp    = wsb + 24 * M1;
  bf16_t* cws   = wsb;  // ctx reuses Qbf region (Qbf dead after proj)

  cvt_kernel<<<dim3(512, 1, 16), 256, 0, stream>>>(Q, K, V, wq, wk, wv, wout, wsb);
  proj_kernel<<<dim3(32, 16, 3), 256, 0, stream>>>(Qbf, Kbf, Vbf, wqb, wkb, wvb, qp, kp, vp);
  attn_kernel<<<dim3(32, 32), 256, 0, stream>>>(qp, kp, vp, cws);
  out_kernel<<<dim3(32, 16), 256, 0, stream>>>(cws, woutb, out);
}